// Round 5
// baseline (238.842 us; speedup 1.0000x reference)
//
#include <hip/hip_runtime.h>
#include <math.h>

// B=32, S=4096, D=256  (fp32). MAX_LEN=5000.
// out[b,s,d] = nodes[b,s,d] + (s <= num_nodes[b] ? pe[(s-num_nodes[b]) mod 5000, d] : 0)
// pe[p, 2k]   = sin(p * div[k]),  pe[p, 2k+1] = cos(p * div[k])
// div[k] = exp2(-log2(10000) * 2k / 256)
//
// Roofline: 134 MB read + 134 MB write -> ~43 us at 6.3 TB/s HBM; if the input
// stays LLC-resident across bench iterations (134 MB < 256 MiB LLC), the floor
// is ~21-25 us (write-only HBM traffic). v0 (1 float4/thread, 32768 blocks)
// measured 218.6 us = dispatch/latency-bound (~150 blocks/us), not BW.
//
// Design: persistent grid-stride, 2048 blocks, 4-deep batched independent
// loads (16 float4/thread), EXACT guard-free path for the real shape,
// readfirstlane-scalarized num_nodes load (one s_load per wave).
// Regular (allocating) load so nodes can persist in LLC across iterations;
// nontemporal store so the never-re-read out stream doesn't evict it.
//
// NOTE: resubmitted unchanged again (rounds 0-4 all failed on GPU
// acquisition; this design has never been measured — no blind edit stacking).

typedef float v4f __attribute__((ext_vector_type(4)));

#define BLOCK 256
#define BATCH 4

template <bool EXACT>
__global__ __launch_bounds__(BLOCK) void rpe_kernel(const float* __restrict__ nodes,
                                                    const int* __restrict__ num_nodes,
                                                    float* __restrict__ out,
                                                    const int total4) {
    const int stride = gridDim.x * BLOCK;        // float4 stride; multiple of 64
    const int tid    = blockIdx.x * BLOCK + threadIdx.x;

    // d4 = float4 index within the 256-float row; invariant across grid-stride
    // iterations because stride % 64 == 0. One wave == one row per batch item,
    // so s and b are wave-uniform and the s<=nn branch doesn't diverge.
    const int d4 = tid & 63;
    const float cexp   = -0.051905126482062035f;  // -log2(10000)/256
    const float inv2pi = 0.15915494309189535f;
    const float f0 = exp2f(cexp * (float)(4 * d4)) * inv2pi;      // revolutions/pos
    const float f1 = exp2f(cexp * (float)(4 * d4 + 2)) * inv2pi;

    for (int base = tid; base < total4; base += stride * BATCH) {
        int idx[BATCH];
        v4f v[BATCH];
        int nn[BATCH];

        // Issue all BATCH independent loads before any dependent use.
        #pragma unroll
        for (int k = 0; k < BATCH; ++k) {
            idx[k] = base + k * stride;
            if (EXACT || idx[k] < total4) {
                // Regular (cache-allocating) load: nodes fits in the 256 MiB
                // LLC and may be reused across bench iterations.
                v[k] = reinterpret_cast<const v4f*>(nodes)[idx[k]];
                // b = idx >> 18 is wave-uniform; readfirstlane makes the
                // address scalar so this compiles to s_load_dword (1/wave).
                const int b = __builtin_amdgcn_readfirstlane(idx[k] >> 18);
                nn[k] = num_nodes[b];
            }
        }

        #pragma unroll
        for (int k = 0; k < BATCH; ++k) {
            if (!EXACT && idx[k] >= total4) break;
            const int s = (idx[k] >> 6) & 4095;    // sequence position (wave-uniform)
            v4f w = v[k];
            if (s <= nn[k]) {                      // wave-uniform branch
                int r = s - nn[k];                 // r in (-4096, 0]
                int p = (r < 0) ? r + 5000 : r;    // Python mod semantics
                const float pf = (float)p;

                float r0 = pf * f0;  r0 -= floorf(r0);   // [0,1) revolutions
                float r1 = pf * f1;  r1 -= floorf(r1);

                w.x += __builtin_amdgcn_sinf(r0);  // v_sin_f32: sin(2*pi*r0)
                w.y += __builtin_amdgcn_cosf(r0);
                w.z += __builtin_amdgcn_sinf(r1);
                w.w += __builtin_amdgcn_cosf(r1);
            }
            // Nontemporal store: out is never re-read; don't let the write
            // stream evict nodes from the LLC.
            __builtin_nontemporal_store(w, reinterpret_cast<v4f*>(out) + idx[k]);
        }
    }
}

extern "C" void kernel_launch(void* const* d_in, const int* in_sizes, int n_in,
                              void* d_out, int out_size, void* d_ws, size_t ws_size,
                              hipStream_t stream) {
    const float* nodes     = (const float*)d_in[0];
    const int*   num_nodes = (const int*)d_in[1];
    float*       out       = (float*)d_out;

    // total float4 elements: 32*4096*256/4 = 8388608
    const int total4 = out_size / 4;

    // Persistent-style grid: cap at 2048 blocks (8 blocks/CU), grid-stride the rest.
    int grid = (total4 + BLOCK * BATCH - 1) / (BLOCK * BATCH);
    if (grid > 2048) grid = 2048;

    const long long chunk = (long long)grid * BLOCK * BATCH;
    if (total4 % chunk == 0) {
        // Real shape: 8388608 = 4 * (2048*256*4) -> guard-free, fully unrolled.
        rpe_kernel<true><<<grid, BLOCK, 0, stream>>>(nodes, num_nodes, out, total4);
    } else {
        rpe_kernel<false><<<grid, BLOCK, 0, stream>>>(nodes, num_nodes, out, total4);
    }
}

// Round 6
// 238.545 us; speedup vs baseline: 1.0012x; 1.0012x over previous
//
#include <hip/hip_runtime.h>
#include <math.h>

// B=32, S=4096, D=256  (fp32). MAX_LEN=5000.
// out[b,s,d] = nodes[b,s,d] + (s <= num_nodes[b] ? pe[(s-num_nodes[b]) mod 5000, d] : 0)
//
// Measured (round 5): 84.5 us/dispatch, 2.39 TB/s, FETCH 64 MB (half of input
// LLC-resident), WRITE 134 MB, VALUBusy 4.4%, VGPR_Count=16.
// VGPR=16 proves the compiler serialized the 4-deep load batch (4xfloat4 data
// alone needs 16 VGPRs; it sank each load to its use and recycled regs) ->
// effective MLP ~1-2, latency-margin-bound at 38% of the 6.3 TB/s ceiling.
// This round's single change: named load registers + sched_barrier(0) fence
// after the load cluster so all 4 float4 loads (+ scalar num_nodes loads)
// are in flight before the first use. Everything else frozen.

typedef float v4f __attribute__((ext_vector_type(4)));

#define BLOCK 256
#define BATCH 4

__device__ __forceinline__ void pe_add_store(v4f w, int idx, int nn,
                                             float f0, float f1,
                                             float* __restrict__ out) {
    const int s = (idx >> 6) & 4095;       // sequence position (wave-uniform)
    if (s <= nn) {                         // wave-uniform branch
        int r = s - nn;                    // r in (-4096, 0]
        int p = (r < 0) ? r + 5000 : r;    // Python mod semantics
        const float pf = (float)p;
        float r0 = pf * f0;  r0 -= floorf(r0);   // [0,1) revolutions
        float r1 = pf * f1;  r1 -= floorf(r1);
        w.x += __builtin_amdgcn_sinf(r0);  // v_sin_f32: sin(2*pi*r0)
        w.y += __builtin_amdgcn_cosf(r0);
        w.z += __builtin_amdgcn_sinf(r1);
        w.w += __builtin_amdgcn_cosf(r1);
    }
    // Nontemporal store: out is never re-read; don't evict nodes from LLC.
    __builtin_nontemporal_store(w, reinterpret_cast<v4f*>(out) + idx);
}

template <bool EXACT>
__global__ __launch_bounds__(BLOCK) void rpe_kernel(const float* __restrict__ nodes,
                                                    const int* __restrict__ num_nodes,
                                                    float* __restrict__ out,
                                                    const int total4) {
    const int stride = gridDim.x * BLOCK;        // float4 stride; multiple of 64
    const int tid    = blockIdx.x * BLOCK + threadIdx.x;

    // d4 invariant across grid-stride iterations (stride % 64 == 0); one wave
    // == one row per batch item, so s and b are wave-uniform.
    const int d4 = tid & 63;
    const float cexp   = -0.051905126482062035f;  // -log2(10000)/256
    const float inv2pi = 0.15915494309189535f;
    const float f0 = exp2f(cexp * (float)(4 * d4)) * inv2pi;      // revolutions/pos
    const float f1 = exp2f(cexp * (float)(4 * d4 + 2)) * inv2pi;

    const v4f* __restrict__ in4 = reinterpret_cast<const v4f*>(nodes);

    if (EXACT) {
        for (int base = tid; base < total4; base += stride * BATCH) {
            const int i0 = base;
            const int i1 = base + stride;
            const int i2 = base + 2 * stride;
            const int i3 = base + 3 * stride;

            // --- load cluster: all VMEM + scalar loads issued here ---
            const int n0 = num_nodes[__builtin_amdgcn_readfirstlane(i0 >> 18)];
            const int n1 = num_nodes[__builtin_amdgcn_readfirstlane(i1 >> 18)];
            const int n2 = num_nodes[__builtin_amdgcn_readfirstlane(i2 >> 18)];
            const int n3 = num_nodes[__builtin_amdgcn_readfirstlane(i3 >> 18)];
            v4f v0 = in4[i0];
            v4f v1 = in4[i1];
            v4f v2 = in4[i2];
            v4f v3 = in4[i3];
            // Fence: nothing may be scheduled across this point, so the
            // compiler cannot sink loads to their uses / recycle the data
            // registers. Forces 4 loads in flight per thread (MLP=4).
            __builtin_amdgcn_sched_barrier(0);

            // --- drain: vmcnt(3)->use v0, vmcnt(2)->v1, ... ---
            pe_add_store(v0, i0, n0, f0, f1, out);
            pe_add_store(v1, i1, n1, f0, f1, out);
            pe_add_store(v2, i2, n2, f0, f1, out);
            pe_add_store(v3, i3, n3, f0, f1, out);
        }
    } else {
        for (int base = tid; base < total4; base += stride * BATCH) {
            int idx[BATCH];
            v4f v[BATCH];
            int nn[BATCH];
            #pragma unroll
            for (int k = 0; k < BATCH; ++k) {
                idx[k] = base + k * stride;
                if (idx[k] < total4) {
                    v[k]  = in4[idx[k]];
                    nn[k] = num_nodes[__builtin_amdgcn_readfirstlane(idx[k] >> 18)];
                }
            }
            #pragma unroll
            for (int k = 0; k < BATCH; ++k) {
                if (idx[k] >= total4) break;
                pe_add_store(v[k], idx[k], nn[k], f0, f1, out);
            }
        }
    }
}

extern "C" void kernel_launch(void* const* d_in, const int* in_sizes, int n_in,
                              void* d_out, int out_size, void* d_ws, size_t ws_size,
                              hipStream_t stream) {
    const float* nodes     = (const float*)d_in[0];
    const int*   num_nodes = (const int*)d_in[1];
    float*       out       = (float*)d_out;

    // total float4 elements: 32*4096*256/4 = 8388608
    const int total4 = out_size / 4;

    // Persistent grid: 2048 blocks (8 blocks/CU = 32 waves/CU), grid-stride.
    int grid = (total4 + BLOCK * BATCH - 1) / (BLOCK * BATCH);
    if (grid > 2048) grid = 2048;

    const long long chunk = (long long)grid * BLOCK * BATCH;
    if (total4 % chunk == 0) {
        // Real shape: 8388608 = 4 * (2048*256*4) -> guard-free, fully unrolled.
        rpe_kernel<true><<<grid, BLOCK, 0, stream>>>(nodes, num_nodes, out, total4);
    } else {
        rpe_kernel<false><<<grid, BLOCK, 0, stream>>>(nodes, num_nodes, out, total4);
    }
}

// Round 7
// 219.474 us; speedup vs baseline: 1.0882x; 1.0869x over previous
//
#include <hip/hip_runtime.h>
#include <math.h>

// B=32, S=4096, D=256  (fp32). MAX_LEN=5000.
// out[b,s,d] = nodes[b,s,d] + (s <= num_nodes[b] ? pe[(s-num_nodes[b]) mod 5000, d] : 0)
// pe[p, 2k] = sin(p * div[k]), pe[p, 2k+1] = cos(p * div[k]), div[k] = exp2(-log2(1e4)*2k/256)
//
// History / evidence:
//  - v0 (this structure: flat grid, 1 float4/thread, NT load + NT store):
//    headline 218.6 us => inferred ~65 us/dispatch (C ~= 154 us harness overhead).
//  - r5/r6 (persistent 2048-block grid-stride, regular load + NT store, 4-deep
//    batch): 84.5-85.2 us/dispatch, 2.38 TB/s HBM, FETCH=64 MB (48% input LLC
//    hit => NT stores DO allocate in LLC), VALUBusy 4.4%, VGPR=16.
//    sched_barrier load-cluster: zero delta => MLP/latency theory falsified
//    (at 17 waves/CU even MLP=1 exceeds the latency-BW product).
//  => The persistent redesign REGRESSED vs v0. Suspects: regular-load LLC
//     thrash (268 MB/iter through a 256 MB LLC) and/or scattered 4x8MB-window
//     access pattern vs v0's contiguous sweep.
//
// This round: faithful v0 reproduction to (a) get counters on the fastest
// known structure, (b) establish the base for one-variable policy A/Bs.
// Predict: ~60-70 us/dispatch, FETCH ~134 MB, WRITE ~134 MB.

typedef float v4f __attribute__((ext_vector_type(4)));

__global__ __launch_bounds__(256) void rpe_kernel(const float* __restrict__ nodes,
                                                  const int* __restrict__ num_nodes,
                                                  float* __restrict__ out,
                                                  const int total4) {
    const int tid = blockIdx.x * blockDim.x + threadIdx.x;  // one float4 per thread
    if (tid >= total4) return;                              // never taken at real shape

    const int d4 = tid & 63;           // float4 index within row (64 per row)
    const int s  = (tid >> 6) & 4095;  // sequence position
    const int b  = tid >> 18;          // batch

    const int nn = num_nodes[b];       // wave-uniform (one wave == one row)

    v4f v = __builtin_nontemporal_load(reinterpret_cast<const v4f*>(nodes) + tid);

    if (s <= nn) {                     // wave-uniform branch
        int r = s - nn;                // r in (-4096, 0]
        int p = (r < 0) ? r + 5000 : r;  // Python mod semantics
        const float pf = (float)p;

        // f[k] = div[k] / (2*pi)  (revolutions per unit position)
        const float cexp   = -0.051905126482062035f;  // -log2(10000)/256
        const float inv2pi = 0.15915494309189535f;
        const float f0 = exp2f(cexp * (float)(4 * d4)) * inv2pi;
        const float f1 = exp2f(cexp * (float)(4 * d4 + 2)) * inv2pi;

        float r0 = pf * f0;  r0 -= floorf(r0);   // [0,1) revolutions
        float r1 = pf * f1;  r1 -= floorf(r1);

        v.x += __builtin_amdgcn_sinf(r0);   // v_sin_f32: sin(2*pi*r0)
        v.y += __builtin_amdgcn_cosf(r0);
        v.z += __builtin_amdgcn_sinf(r1);
        v.w += __builtin_amdgcn_cosf(r1);
    }

    __builtin_nontemporal_store(v, reinterpret_cast<v4f*>(out) + tid);
}

extern "C" void kernel_launch(void* const* d_in, const int* in_sizes, int n_in,
                              void* d_out, int out_size, void* d_ws, size_t ws_size,
                              hipStream_t stream) {
    const float* nodes     = (const float*)d_in[0];
    const int*   num_nodes = (const int*)d_in[1];
    float*       out       = (float*)d_out;

    // total float4 elements: 32*4096*256/4 = 8388608 -> 32768 blocks of 256
    const int total4 = out_size / 4;
    const int block  = 256;
    const int grid   = (total4 + block - 1) / block;

    rpe_kernel<<<grid, block, 0, stream>>>(nodes, num_nodes, out, total4);
}